// Round 1
// 9071.758 us; speedup vs baseline: 1.0057x; 1.0057x over previous
//
#include <hip/hip_runtime.h>

#define NN 512
#define DD 32
#define TT 8192

typedef float v4f __attribute__((ext_vector_type(4)));
typedef float v2f __attribute__((ext_vector_type(2)));
typedef __attribute__((address_space(3))) float lds_f;
typedef __attribute__((address_space(3))) void lds_v;
typedef const __attribute__((address_space(1))) void glb_v;

constexpr float F_OMEGA = 10.0f;
constexpr float F_DT = 1e-3f;
constexpr float F_TWO_PI = 6.28318530717958647692f;
constexpr float F_INV_TWO_PI = 0.15915494309189533577f;

// Barrier waiting LDS/SMEM only (lgkmcnt), never vmcnt: glds prefetches and
// output stores stay in flight across the per-step sync.
__device__ __forceinline__ void barrier_lgkm() {
    asm volatile("s_waitcnt lgkmcnt(0)\n\ts_barrier" ::: "memory");
}

// Async global->LDS stage, vmcnt-tracked. Wave-uniform LDS base + lane*4.
__device__ __forceinline__ void glds4(const float* g, lds_f* dst) {
    __builtin_amdgcn_global_load_lds((glb_v*)g, (lds_v*)dst, 4, 0, 0);
}

// Asm-laundered LDS reads: compiler cannot scalarize them, cannot hoist uses
// above the tied lgkm wait, and does not know they alias the glds buffers
// (so it cannot insert a conservative vmcnt(0) drain).
#define DSR128(dst, addr, off) \
    asm volatile("ds_read_b128 %0, %1 offset:" #off : "=v"(dst) : "v"(addr))
#define DSR32(dst, addr, off) \
    asm volatile("ds_read_b32 %0, %1 offset:" #off : "=v"(dst) : "v"(addr))

// Forced packed-FP32 (VOP3P). Non-volatile: scheduler may interleave freely;
// ordering is enforced purely by register data deps. Each op is FP-identical
// to the two scalar ops it replaces.
#define PK_MUL(d, a, b) /* d = a*b (init: == fma(a,b,0)) */ \
    asm("v_pk_mul_f32 %0, %1, %2" : "=v"(d) : "v"(a), "v"(b))
#define PK_FMA_ACC(d, a, b) /* d = a*b + d */ \
    asm("v_pk_fma_f32 %0, %1, %2, %0" : "+v"(d) : "v"(a), "v"(b))
#define PK_FMA_W(w, m, t) /* w = w*m + t */ \
    asm("v_pk_fma_f32 %0, %0, %1, %2" : "+v"(w) : "v"(m), "v"(t))

// One step of a DPP-based wave64 reduction: x += dpp_move(x).
#define DPP_ADD(x, ctrl, rmask)                                                 \
    {                                                                           \
        int _t = __builtin_amdgcn_update_dpp(0, __float_as_int(x),              \
                                             (ctrl), (rmask), 0xf, true);       \
        (x) += __int_as_float(_t);                                              \
    }

__device__ __forceinline__ float wave_reduce_to_lane63(float x) {
    DPP_ADD(x, 0xB1, 0xf);   // + xor1
    DPP_ADD(x, 0x4E, 0xf);   // + xor2
    DPP_ADD(x, 0x141, 0xf);  // + xor4
    DPP_ADD(x, 0x140, 0xf);  // + xor8
    DPP_ADD(x, 0x142, 0xa);  // row_bcast15
    DPP_ADD(x, 0x143, 0xc);  // row_bcast31
    return x;                // lane 63 = full wave sum
}

__global__ __launch_bounds__(512, 2) void deerskin(
    const float* __restrict__ Xr, const float* __restrict__ Xi,
    const float* __restrict__ Tg,
    const float* __restrict__ W0r, const float* __restrict__ W0i,
    const float* __restrict__ Phi0, const float* __restrict__ Beta0,
    float* __restrict__ outs, float* __restrict__ betas, float* __restrict__ gammas)
{
    // 3 x-staging buffers (72 floats = 288B each: [0..31]=xr, [32..63]=xi,
    // [64]=tgt) + 16-float double-buffered partial array.
    __shared__ __align__(16) float xbuf[3][72];
    __shared__ __align__(16) float sP[16];

    const int n = threadIdx.x;
    const int lane = n & 63;
    const int wid = n >> 6;

    // W row in registers as v2f[16] per re/im (64 VGPRs each) so every hot op
    // maps 1:1 onto a v_pk_{mul,fma}_f32.
    v2f wr2[16], wi2[16];
    {
        const v2f* wr0 = (const v2f*)(W0r + n * DD);
        const v2f* wi0 = (const v2f*)(W0i + n * DD);
#pragma unroll
        for (int k = 0; k < 16; ++k) { wr2[k] = wr0[k]; wi2[k] = wi0[k]; }
    }
    float phi = Phi0[n];
    float beta = Beta0[n];
    float lt = 0.0f;
    float err = 0.0f;

    // Per-lane glds source: lanes 0..31 cover the Xr row, 32..63 the Xi row.
    const float* xsrc = ((lane < 32) ? Xr : Xi) + (lane & 31);

    lds_f* pcur = (lds_f*)&xbuf[0][0];
    lds_f* pnxt = (lds_f*)&xbuf[1][0];
    lds_f* pfut = (lds_f*)&xbuf[2][0];

    // ---- prologue: stage x(0) -> buf0, x(1) -> buf1; wave 0 drains, all sync.
    if (wid == 0) {
        glds4(xsrc, pcur);
        glds4(xsrc + DD, pnxt);
        if (lane == 0) {
            glds4(Tg, pcur + 64);
            glds4(Tg + 1, pnxt + 64);
        }
        asm volatile("s_waitcnt vmcnt(0)" ::: "memory");
    }
    barrier_lgkm();

    for (int t = 0; t < TT; ++t) {
        // ---- 1. stage x(t+2) into the future buffer (wave 0; vmcnt-tracked,
        // drained only by the counted wait 2 steps of slack later).
        if (wid == 0) {
            int tf = t + 2; tf = (tf < TT) ? tf : (TT - 1);
            glds4(xsrc + (size_t)tf * DD, pfut);
            if (lane == 0) glds4(Tg + tf, pfut + 64);
        }

        // ---- 2. x-independent precompute (fills staging latency) ----
        const float gamma = __expf(-0.5f * beta);
        const float dtl = gamma * F_DT;
        lt += dtl;
        const float theta = fmaf(F_OMEGA, lt, phi);
        float rev = theta * F_INV_TWO_PI;
        rev -= floorf(rev);
        const float s = __builtin_amdgcn_sinf(rev);
        const float c = __builtin_amdgcn_cosf(rev);
        const float a_sA = 1.0f - __expf(-2.0f * F_DT * (gamma + 1e-6f));
        const float a_sB = 1.0f - __expf(-F_DT / 0.03f);

        // ---- 3. x(t) from LDS via laundered ds_read + tied lgkm wait ----
        const unsigned lcur = (unsigned)(unsigned long long)pcur;
        v4f cr[8], ci[8];
        float tgt;
        DSR128(cr[0], lcur, 0);   DSR128(cr[1], lcur, 16);
        DSR128(cr[2], lcur, 32);  DSR128(cr[3], lcur, 48);
        DSR128(cr[4], lcur, 64);  DSR128(cr[5], lcur, 80);
        DSR128(cr[6], lcur, 96);  DSR128(cr[7], lcur, 112);
        DSR128(ci[0], lcur, 128); DSR128(ci[1], lcur, 144);
        DSR128(ci[2], lcur, 160); DSR128(ci[3], lcur, 176);
        DSR128(ci[4], lcur, 192); DSR128(ci[5], lcur, 208);
        DSR128(ci[6], lcur, 224); DSR128(ci[7], lcur, 240);
        DSR32(tgt, lcur, 256);
        asm volatile("s_waitcnt lgkmcnt(0)"
            : "+v"(cr[0]), "+v"(cr[1]), "+v"(cr[2]), "+v"(cr[3]),
              "+v"(cr[4]), "+v"(cr[5]), "+v"(cr[6]), "+v"(cr[7]),
              "+v"(ci[0]), "+v"(ci[1]), "+v"(ci[2]), "+v"(ci[3]),
              "+v"(ci[4]), "+v"(ci[5]), "+v"(ci[6]), "+v"(ci[7]),
              "+v"(tgt) :: "memory");

        // Split the quads into packed halves (subregister views; derived from
        // the post-wait values so nothing can be hoisted above the wait).
        v2f xr_[16], xi_[16];
#pragma unroll
        for (int j = 0; j < 8; ++j) {
            xr_[2 * j]     = __builtin_shufflevector(cr[j], cr[j], 0, 1);
            xr_[2 * j + 1] = __builtin_shufflevector(cr[j], cr[j], 2, 3);
            xi_[2 * j]     = __builtin_shufflevector(ci[j], ci[j], 0, 1);
            xi_[2 * j + 1] = __builtin_shufflevector(ci[j], ci[j], 2, 3);
        }

        // ---- 4. Z = W @ x: 8 packed accumulator chains (64 pk ops), same
        // per-lane accumulation order as the old v4f code ----
        v2f arr0, arr1, aii0, aii1, ari0, ari1, air0, air1;
        PK_MUL(arr0, wr2[0], xr_[0]); PK_MUL(arr1, wr2[1], xr_[1]);
        PK_MUL(aii0, wi2[0], xi_[0]); PK_MUL(aii1, wi2[1], xi_[1]);
        PK_MUL(ari0, wr2[0], xi_[0]); PK_MUL(ari1, wr2[1], xi_[1]);
        PK_MUL(air0, wi2[0], xr_[0]); PK_MUL(air1, wi2[1], xr_[1]);
#pragma unroll
        for (int k = 2; k < 16; k += 2) {
            PK_FMA_ACC(arr0, wr2[k], xr_[k]); PK_FMA_ACC(arr1, wr2[k + 1], xr_[k + 1]);
            PK_FMA_ACC(aii0, wi2[k], xi_[k]); PK_FMA_ACC(aii1, wi2[k + 1], xi_[k + 1]);
            PK_FMA_ACC(ari0, wr2[k], xi_[k]); PK_FMA_ACC(ari1, wr2[k + 1], xi_[k + 1]);
            PK_FMA_ACC(air0, wi2[k], xr_[k]); PK_FMA_ACC(air1, wi2[k + 1], xr_[k + 1]);
        }
        // hsum pairing identical to old (x+y)+(z+w)
        const float hArr = (arr0.x + arr0.y) + (arr1.x + arr1.y);
        const float hAii = (aii0.x + aii0.y) + (aii1.x + aii1.y);
        const float hAri = (ari0.x + ari0.y) + (ari1.x + ari1.y);
        const float hAir = (air0.x + air0.y) + (air1.x + air1.y);
        const float zr = hArr - hAii;
        const float zi = hAri + hAir;

        // Y = |Z| * relu(cos(theta - angle(Z))) == relu(zr*cos + zi*sin)
        const float Y = fmaxf(fmaf(zr, c, zi * s), 0.0f);

        // ---- 5. reduce 512 -> 1: DPP wave sum, 8 partials via LDS ----
        float v = wave_reduce_to_lane63(Y * c);
        if (lane == 63) sP[((t & 1) << 3) + wid] = v;

        // ---- 6. out-independent precompute (off the post-barrier path) ----
        const float inv_t = 1.0f / (fabsf(tgt) + 0.01f);
        const float yy = Y * Y;
        const float g = 0.05f * Y * dtl;
        phi += (2.0f / (float)NN) * (-tgt * s) * dtl;
        phi = phi - F_TWO_PI * floorf(phi * F_INV_TWO_PI);

        // ---- 7. counted drain of glds(t+1) (wave 0), then sync ----
        // Outstanding newer than glds(t+1): glds(t+2) x2 + stores(t-1) x3 = 5.
        if (wid == 0) asm volatile("s_waitcnt vmcnt(5)" ::: "memory");
        barrier_lgkm();

        // ---- 8. out + short scalar feedback chain ----
        const float4* sp4 = (const float4*)(sP + ((t & 1) << 3));
        const float4 p0 = sp4[0], p1 = sp4[1];
        const float out = ((p0.x + p0.y) + (p0.z + p0.w)) +
                          ((p1.x + p1.y) + (p1.z + p1.w));

        const float raw = fabsf(tgt - out);
        err = 0.99f * err + 0.01f * raw;
        const float rel = err * inv_t;
        const float btg = 3.5f * __expf(-5.0f * rel);
        const float a_s = (btg > beta) ? a_sA : a_sB;
        float bnew = beta + a_s * (btg - beta);
        bnew = fminf(fmaxf(bnew, 0.005f), 5.0f);

        // ---- 9. W = W*m1 + g*x, packed: t = g*x (pk_mul), w = w*m1 + t
        // (pk_fma) — 64 pk ops replacing 128 scalar ops ----
        const float k = (bnew * yy) * dtl;
        const float m1 = 1.0f - k;
        const v2f m12 = {m1, m1};
        const v2f g2 = {g, g};
#pragma unroll
        for (int q = 0; q < 16; ++q) {
            v2f t0, t1;
            PK_MUL(t0, g2, xr_[q]); PK_FMA_W(wr2[q], m12, t0);
            PK_MUL(t1, g2, xi_[q]); PK_FMA_W(wi2[q], m12, t1);
        }

        // ---- 10. outputs: exactly 3 VMEM stores per wave per step (outs via
        // lane 63 of EVERY wave -> identical value, uniform vmcnt count) ----
        gammas[t * NN + n] = gamma;   // gamma from OLD beta, per reference
        betas[t * NN + n] = bnew;
        if (lane == 63) outs[t] = out;
        beta = bnew;

        // ---- 11. rotate staging buffers ----
        lds_f* tmp = pcur; pcur = pnxt; pnxt = pfut; pfut = tmp;
    }
}

extern "C" void kernel_launch(void* const* d_in, const int* in_sizes, int n_in,
                              void* d_out, int out_size, void* d_ws, size_t ws_size,
                              hipStream_t stream) {
    const float* Xr    = (const float*)d_in[0];   // [T, D]
    const float* Xi    = (const float*)d_in[1];   // [T, D]
    const float* Tg    = (const float*)d_in[2];   // [T]
    const float* W0r   = (const float*)d_in[3];   // [N, D]
    const float* W0i   = (const float*)d_in[4];   // [N, D]
    const float* Phi0  = (const float*)d_in[5];   // [N]
    const float* Beta0 = (const float*)d_in[6];   // [N]

    float* outs   = (float*)d_out;                // [T]
    float* betas  = outs + TT;                    // [T, N]
    float* gammas = betas + (size_t)TT * NN;      // [T, N]

    deerskin<<<1, NN, 0, stream>>>(Xr, Xi, Tg, W0r, W0i, Phi0, Beta0,
                                   outs, betas, gammas);
}

// Round 3
// 8874.104 us; speedup vs baseline: 1.0281x; 1.0223x over previous
//
#include <hip/hip_runtime.h>

#define NN 512
#define DD 32
#define TT 8192

typedef float v4f __attribute__((ext_vector_type(4)));
typedef float v2f __attribute__((ext_vector_type(2)));
typedef __attribute__((address_space(3))) float lds_f;
typedef __attribute__((address_space(3))) void lds_v;
typedef const __attribute__((address_space(1))) void glb_v;

constexpr float F_OMEGA = 10.0f;
constexpr float F_DT = 1e-3f;
constexpr float F_TWO_PI = 6.28318530717958647692f;
constexpr float F_INV_TWO_PI = 0.15915494309189533577f;

// Barrier waiting LDS/SMEM only (lgkmcnt), never vmcnt: glds prefetches and
// output stores stay in flight across the per-step sync.
__device__ __forceinline__ void barrier_lgkm() {
    asm volatile("s_waitcnt lgkmcnt(0)\n\ts_barrier" ::: "memory");
}

// Async global->LDS stage, vmcnt-tracked. Wave-uniform LDS base + lane*4.
__device__ __forceinline__ void glds4(const float* g, lds_f* dst) {
    __builtin_amdgcn_global_load_lds((glb_v*)g, (lds_v*)dst, 4, 0, 0);
}

// Asm-laundered LDS reads: compiler cannot scalarize them, cannot hoist uses
// above the tied lgkm wait, and does not know they alias the glds buffers
// (so it cannot insert a conservative vmcnt(0) drain).
#define DSR128(dst, addr, off) \
    asm volatile("ds_read_b128 %0, %1 offset:" #off : "=v"(dst) : "v"(addr))
#define DSR32(dst, addr, off) \
    asm volatile("ds_read_b32 %0, %1 offset:" #off : "=v"(dst) : "v"(addr))

// Forced packed-FP32 (VOP3P). Non-volatile: scheduler may interleave freely;
// ordering is enforced purely by register data deps. Each op is FP-identical
// to the two scalar ops it replaces.
#define PK_MUL(d, a, b) /* d = a*b */ \
    asm("v_pk_mul_f32 %0, %1, %2" : "=v"(d) : "v"(a), "v"(b))
#define PK_FMA_ACC(d, a, b) /* d = a*b + d */ \
    asm("v_pk_fma_f32 %0, %1, %2, %0" : "+v"(d) : "v"(a), "v"(b))
#define PK_FMA_W(w, m, t) /* w = w*m + t */ \
    asm("v_pk_fma_f32 %0, %0, %1, %2" : "+v"(w) : "v"(m), "v"(t))

// One step of a DPP-based wave64 reduction: x += dpp_move(x).
#define DPP_ADD(x, ctrl, rmask)                                                 \
    {                                                                           \
        int _t = __builtin_amdgcn_update_dpp(0, __float_as_int(x),              \
                                             (ctrl), (rmask), 0xf, true);       \
        (x) += __int_as_float(_t);                                              \
    }

__device__ __forceinline__ float wave_reduce_to_lane63(float x) {
    DPP_ADD(x, 0xB1, 0xf);   // + xor1
    DPP_ADD(x, 0x4E, 0xf);   // + xor2
    DPP_ADD(x, 0x141, 0xf);  // + xor4
    DPP_ADD(x, 0x140, 0xf);  // + xor8
    DPP_ADD(x, 0x142, 0xa);  // row_bcast15
    DPP_ADD(x, 0x143, 0xc);  // row_bcast31
    return x;                // lane 63 = full wave sum
}

__global__ __launch_bounds__(512, 2) void deerskin(
    const float* __restrict__ Xr, const float* __restrict__ Xi,
    const float* __restrict__ Tg,
    const float* __restrict__ W0r, const float* __restrict__ W0i,
    const float* __restrict__ Phi0, const float* __restrict__ Beta0,
    float* __restrict__ outs, float* __restrict__ betas, float* __restrict__ gammas)
{
    // 3 x-staging buffers (72 floats = 288B each: [0..31]=xr, [32..63]=xi,
    // [64]=tgt) + 16-float double-buffered partial array.
    __shared__ __align__(16) float xbuf[3][72];
    __shared__ __align__(16) float sP[16];

    const int n = threadIdx.x;
    const int lane = n & 63;
    const int wid = n >> 6;

    // W row in registers as v2f[16] per re/im so every hot op maps 1:1 onto
    // a v_pk_{mul,fma}_f32.
    v2f wr2[16], wi2[16];
    {
        const v2f* wr0 = (const v2f*)(W0r + n * DD);
        const v2f* wi0 = (const v2f*)(W0i + n * DD);
#pragma unroll
        for (int k = 0; k < 16; ++k) { wr2[k] = wr0[k]; wi2[k] = wi0[k]; }
    }
    float phi = Phi0[n];
    float beta = Beta0[n];
    float lt = 0.0f;
    float err = 0.0f;

    // Per-lane glds source: lanes 0..31 cover the Xr row, 32..63 the Xi row.
    const float* xsrc = ((lane < 32) ? Xr : Xi) + (lane & 31);

    lds_f* pcur = (lds_f*)&xbuf[0][0];
    lds_f* pnxt = (lds_f*)&xbuf[1][0];
    lds_f* pfut = (lds_f*)&xbuf[2][0];

    // Loop-carried x registers: cr/ci/tgt_nxt hold x(t) at the top of step t.
    // They are refilled (same registers) in the post-barrier phase of step t
    // with x(t+1) — the last use of x(t) (tw compute) is pre-barrier, so the
    // lifetimes do not overlap and no double-buffering is needed.
    v4f cr[8], ci[8];
    float tgt_nxt;

    // ---- prologue: stage x(0)->buf0, x(1)->buf1; wave 0 drains; all sync;
    // then pull x(0) into registers (drained by the tie-wait at t=0).
    if (wid == 0) {
        glds4(xsrc, pcur);
        glds4(xsrc + DD, pnxt);
        if (lane == 0) {
            glds4(Tg, pcur + 64);
            glds4(Tg + 1, pnxt + 64);
        }
        asm volatile("s_waitcnt vmcnt(0)" ::: "memory");
    }
    barrier_lgkm();
    {
        const unsigned l0 = (unsigned)(unsigned long long)pcur;
        DSR128(cr[0], l0, 0);   DSR128(cr[1], l0, 16);
        DSR128(cr[2], l0, 32);  DSR128(cr[3], l0, 48);
        DSR128(cr[4], l0, 64);  DSR128(cr[5], l0, 80);
        DSR128(cr[6], l0, 96);  DSR128(cr[7], l0, 112);
        DSR128(ci[0], l0, 128); DSR128(ci[1], l0, 144);
        DSR128(ci[2], l0, 160); DSR128(ci[3], l0, 176);
        DSR128(ci[4], l0, 192); DSR128(ci[5], l0, 208);
        DSR128(ci[6], l0, 224); DSR128(ci[7], l0, 240);
        DSR32(tgt_nxt, l0, 256);
    }

    for (int t = 0; t < TT; ++t) {
        // ---- A. stage x(t+2) into the future buffer (wave 0; vmcnt-tracked,
        // drained only by the counted wait 2 steps of slack later).
        if (wid == 0) {
            int tf = t + 2; tf = (tf < TT) ? tf : (TT - 1);
            glds4(xsrc + (size_t)tf * DD, pfut);
            if (lane == 0) glds4(Tg + tf, pfut + 64);
        }

        // ---- B. tie-wait for x(t): issued a half-step ago (post-barrier of
        // t-1), so this wait is ~free. Then build pair views.
        asm volatile("s_waitcnt lgkmcnt(0)"
            : "+v"(cr[0]), "+v"(cr[1]), "+v"(cr[2]), "+v"(cr[3]),
              "+v"(cr[4]), "+v"(cr[5]), "+v"(cr[6]), "+v"(cr[7]),
              "+v"(ci[0]), "+v"(ci[1]), "+v"(ci[2]), "+v"(ci[3]),
              "+v"(ci[4]), "+v"(ci[5]), "+v"(ci[6]), "+v"(ci[7]),
              "+v"(tgt_nxt) :: "memory");
        const float tgt = tgt_nxt;

        v2f xr_[16], xi_[16];
#pragma unroll
        for (int j = 0; j < 8; ++j) {
            xr_[2 * j]     = __builtin_shufflevector(cr[j], cr[j], 0, 1);
            xr_[2 * j + 1] = __builtin_shufflevector(cr[j], cr[j], 2, 3);
            xi_[2 * j]     = __builtin_shufflevector(ci[j], ci[j], 0, 1);
            xi_[2 * j + 1] = __builtin_shufflevector(ci[j], ci[j], 2, 3);
        }

        // ---- B2. x-independent precompute ----
        const float gamma = __expf(-0.5f * beta);
        const float dtl = gamma * F_DT;
        lt += dtl;
        const float theta = fmaf(F_OMEGA, lt, phi);
        float rev = theta * F_INV_TWO_PI;
        rev -= floorf(rev);
        const float s = __builtin_amdgcn_sinf(rev);
        const float c = __builtin_amdgcn_cosf(rev);
        const float a_sA = 1.0f - __expf(-2.0f * F_DT * (gamma + 1e-6f));
        const float a_sB = 1.0f - __expf(-F_DT / 0.03f);

        // ---- D. Z = W @ x: 8 packed accumulator chains, same per-lane
        // accumulation order as before ----
        v2f arr0, arr1, aii0, aii1, ari0, ari1, air0, air1;
        PK_MUL(arr0, wr2[0], xr_[0]); PK_MUL(arr1, wr2[1], xr_[1]);
        PK_MUL(aii0, wi2[0], xi_[0]); PK_MUL(aii1, wi2[1], xi_[1]);
        PK_MUL(ari0, wr2[0], xi_[0]); PK_MUL(ari1, wr2[1], xi_[1]);
        PK_MUL(air0, wi2[0], xr_[0]); PK_MUL(air1, wi2[1], xr_[1]);
#pragma unroll
        for (int k = 2; k < 16; k += 2) {
            PK_FMA_ACC(arr0, wr2[k], xr_[k]); PK_FMA_ACC(arr1, wr2[k + 1], xr_[k + 1]);
            PK_FMA_ACC(aii0, wi2[k], xi_[k]); PK_FMA_ACC(aii1, wi2[k + 1], xi_[k + 1]);
            PK_FMA_ACC(ari0, wr2[k], xi_[k]); PK_FMA_ACC(ari1, wr2[k + 1], xi_[k + 1]);
            PK_FMA_ACC(air0, wi2[k], xr_[k]); PK_FMA_ACC(air1, wi2[k + 1], xr_[k + 1]);
        }
        const float hArr = (arr0.x + arr0.y) + (arr1.x + arr1.y);
        const float hAii = (aii0.x + aii0.y) + (aii1.x + aii1.y);
        const float hAri = (ari0.x + ari0.y) + (ari1.x + ari1.y);
        const float hAir = (air0.x + air0.y) + (air1.x + air1.y);
        const float zr = hArr - hAii;
        const float zi = hAri + hAir;

        // Y = |Z| * relu(cos(theta - angle(Z))) == relu(zr*cos + zi*sin)
        const float Y = fmaxf(fmaf(zr, c, zi * s), 0.0f);

        // ---- E. reduce 512 -> 1 (DPP + LDS partials), then the x-dependent
        // half of the W update (tw = g*x), hoisted pre-barrier: same ops,
        // same operands, same rounding as before — only scheduled earlier.
        float v = wave_reduce_to_lane63(Y * c);
        if (lane == 63) sP[((t & 1) << 3) + wid] = v;

        const float inv_t = 1.0f / (fabsf(tgt) + 0.01f);
        const float yy = Y * Y;
        const float g = 0.05f * Y * dtl;
        const v2f g2 = {g, g};
        v2f twr[16], twi[16];
#pragma unroll
        for (int q = 0; q < 16; ++q) {
            PK_MUL(twr[q], g2, xr_[q]);
            PK_MUL(twi[q], g2, xi_[q]);
        }
        phi += (2.0f / (float)NN) * (-tgt * s) * dtl;
        phi = phi - F_TWO_PI * floorf(phi * F_INV_TWO_PI);

        // ---- G. counted drain of glds(t+1) (wave 0), then sync ----
        // Outstanding newer than glds(t+1): glds(t+2) x2 + stores(t-1) x3 = 5.
        if (wid == 0) asm volatile("s_waitcnt vmcnt(5)" ::: "memory");
        barrier_lgkm();

        // ---- I. sP reads, then x(t+1) prefetch into the SAME cr/ci regs.
        // lgkmcnt is a 4-bit field (max 15), so: issue 2 sP reads + 15 x
        // reads, wait lgkmcnt(15) — DS completes in order, so the 2 oldest
        // (sP) are done — then issue the last 2 x reads after the wait
        // (drained by the tie-wait at the top of step t+1).
        const unsigned lsp =
            (unsigned)(unsigned long long)(lds_f*)&sP[(t & 1) << 3];
        const unsigned lnx = (unsigned)(unsigned long long)pnxt;
        v4f p0, p1;
        DSR128(p0, lsp, 0); DSR128(p1, lsp, 16);
        DSR128(cr[0], lnx, 0);   DSR128(cr[1], lnx, 16);
        DSR128(cr[2], lnx, 32);  DSR128(cr[3], lnx, 48);
        DSR128(cr[4], lnx, 64);  DSR128(cr[5], lnx, 80);
        DSR128(cr[6], lnx, 96);  DSR128(cr[7], lnx, 112);
        DSR128(ci[0], lnx, 128); DSR128(ci[1], lnx, 144);
        DSR128(ci[2], lnx, 160); DSR128(ci[3], lnx, 176);
        DSR128(ci[4], lnx, 192); DSR128(ci[5], lnx, 208);
        DSR128(ci[6], lnx, 224);
        asm volatile("s_waitcnt lgkmcnt(15)" : "+v"(p0), "+v"(p1) :: "memory");
        DSR128(ci[7], lnx, 240);
        DSR32(tgt_nxt, lnx, 256);

        // ---- J. out + short scalar feedback chain ----
        const float out = ((p0.x + p0.y) + (p0.z + p0.w)) +
                          ((p1.x + p1.y) + (p1.z + p1.w));
        const float raw = fabsf(tgt - out);
        err = 0.99f * err + 0.01f * raw;
        const float rel = err * inv_t;
        const float btg = 3.5f * __expf(-5.0f * rel);
        const float a_s = (btg > beta) ? a_sA : a_sB;
        float bnew = beta + a_s * (btg - beta);
        bnew = fminf(fmaxf(bnew, 0.005f), 5.0f);

        // ---- K. W = W*m1 + tw: only the m1-dependent half remains on the
        // post-barrier critical path (32 pk_fma, was 64 ops) ----
        const float k = (bnew * yy) * dtl;
        const float m1 = 1.0f - k;
        const v2f m12 = {m1, m1};
#pragma unroll
        for (int q = 0; q < 16; ++q) {
            PK_FMA_W(wr2[q], m12, twr[q]);
            PK_FMA_W(wi2[q], m12, twi[q]);
        }

        // ---- L. outputs: exactly 3 VMEM stores per wave per step (outs via
        // lane 63 of EVERY wave -> identical value, uniform vmcnt count) ----
        gammas[t * NN + n] = gamma;   // gamma from OLD beta, per reference
        betas[t * NN + n] = bnew;
        if (lane == 63) outs[t] = out;
        beta = bnew;

        // ---- rotate staging buffers ----
        lds_f* tmp = pcur; pcur = pnxt; pnxt = pfut; pfut = tmp;
    }
}

extern "C" void kernel_launch(void* const* d_in, const int* in_sizes, int n_in,
                              void* d_out, int out_size, void* d_ws, size_t ws_size,
                              hipStream_t stream) {
    const float* Xr    = (const float*)d_in[0];   // [T, D]
    const float* Xi    = (const float*)d_in[1];   // [T, D]
    const float* Tg    = (const float*)d_in[2];   // [T]
    const float* W0r   = (const float*)d_in[3];   // [N, D]
    const float* W0i   = (const float*)d_in[4];   // [N, D]
    const float* Phi0  = (const float*)d_in[5];   // [N]
    const float* Beta0 = (const float*)d_in[6];   // [N]

    float* outs   = (float*)d_out;                // [T]
    float* betas  = outs + TT;                    // [T, N]
    float* gammas = betas + (size_t)TT * NN;      // [T, N]

    deerskin<<<1, NN, 0, stream>>>(Xr, Xi, Tg, W0r, W0i, Phi0, Beta0,
                                   outs, betas, gammas);
}

// Round 4
// 8505.800 us; speedup vs baseline: 1.0726x; 1.0433x over previous
//
#include <hip/hip_runtime.h>

#define NN 512
#define DD 32
#define TT 8192

typedef float v4f __attribute__((ext_vector_type(4)));
typedef float v2f __attribute__((ext_vector_type(2)));
typedef float v16f __attribute__((ext_vector_type(16)));
typedef __attribute__((address_space(3))) float lds_f;

constexpr float F_OMEGA = 10.0f;
constexpr float F_DT = 1e-3f;
constexpr float F_TWO_PI = 6.28318530717958647692f;
constexpr float F_INV_TWO_PI = 0.15915494309189533577f;

// Barrier waiting LDS/SMEM only (lgkmcnt), never vmcnt: output stores stay
// in flight across the per-step sync. At this point the only outstanding
// lgkm op is lane63's sP ds_write (x prefetch s_loads are issued later).
__device__ __forceinline__ void barrier_lgkm() {
    asm volatile("s_waitcnt lgkmcnt(0)\n\ts_barrier" ::: "memory");
}

// Asm-laundered LDS read for the partial-sum exchange.
#define DSR128(dst, addr, off) \
    asm volatile("ds_read_b128 %0, %1 offset:" #off : "=v"(dst) : "v"(addr))

// Scalar (SMEM) loads: x is wave-uniform, so it lives in SGPRs and the
// scalar cache broadcasts it — this takes the 17 ds_read_b128 per thread
// per step OFF the per-CU LDS pipe (the R0-R3 bottleneck).
#define SL16(dst, ptr, off) \
    asm volatile("s_load_dwordx16 %0, %1, " #off : "=s"(dst) : "s"(ptr))
#define SL1(dst, ptr) \
    asm volatile("s_load_dword %0, %1, 0x0" : "=s"(dst) : "s"(ptr))

// Packed FP32 (VOP3P) with one SGPR-pair source (legal: <=1 SGPR per VALU
// instr). Each op is FP-identical to the VGPR version it replaces: the
// SGPR pair (x[2j],x[2j+1]) is the same 64-bit value the VGPR pair held.
#define PK_MUL_VS(d, a, b) /* d = a*b */ \
    asm("v_pk_mul_f32 %0, %1, %2" : "=v"(d) : "v"(a), "s"(b))
#define PK_FMA_ACC_VS(d, a, b) /* d = a*b + d */ \
    asm("v_pk_fma_f32 %0, %1, %2, %0" : "+v"(d) : "v"(a), "s"(b))
#define PK_FMA_W(w, m, t) /* w = w*m + t */ \
    asm("v_pk_fma_f32 %0, %0, %1, %2" : "+v"(w) : "v"(m), "v"(t))

// One step of a DPP-based wave64 reduction: x += dpp_move(x).
#define DPP_ADD(x, ctrl, rmask)                                                 \
    {                                                                           \
        int _t = __builtin_amdgcn_update_dpp(0, __float_as_int(x),              \
                                             (ctrl), (rmask), 0xf, true);       \
        (x) += __int_as_float(_t);                                              \
    }

__device__ __forceinline__ float wave_reduce_to_lane63(float x) {
    DPP_ADD(x, 0xB1, 0xf);   // + xor1
    DPP_ADD(x, 0x4E, 0xf);   // + xor2
    DPP_ADD(x, 0x141, 0xf);  // + xor4
    DPP_ADD(x, 0x140, 0xf);  // + xor8
    DPP_ADD(x, 0x142, 0xa);  // row_bcast15
    DPP_ADD(x, 0x143, 0xc);  // row_bcast31
    return x;                // lane 63 = full wave sum
}

// Expand two v16f (SGPR-resident) into 16 v2f pair views (SGPR subregs).
#define MKP(dst, lo, hi)                                                        \
    dst[0]  = __builtin_shufflevector(lo, lo, 0, 1);                            \
    dst[1]  = __builtin_shufflevector(lo, lo, 2, 3);                            \
    dst[2]  = __builtin_shufflevector(lo, lo, 4, 5);                            \
    dst[3]  = __builtin_shufflevector(lo, lo, 6, 7);                            \
    dst[4]  = __builtin_shufflevector(lo, lo, 8, 9);                            \
    dst[5]  = __builtin_shufflevector(lo, lo, 10, 11);                          \
    dst[6]  = __builtin_shufflevector(lo, lo, 12, 13);                          \
    dst[7]  = __builtin_shufflevector(lo, lo, 14, 15);                          \
    dst[8]  = __builtin_shufflevector(hi, hi, 0, 1);                            \
    dst[9]  = __builtin_shufflevector(hi, hi, 2, 3);                            \
    dst[10] = __builtin_shufflevector(hi, hi, 4, 5);                            \
    dst[11] = __builtin_shufflevector(hi, hi, 6, 7);                            \
    dst[12] = __builtin_shufflevector(hi, hi, 8, 9);                            \
    dst[13] = __builtin_shufflevector(hi, hi, 10, 11);                          \
    dst[14] = __builtin_shufflevector(hi, hi, 12, 13);                          \
    dst[15] = __builtin_shufflevector(hi, hi, 14, 15);

__global__ __launch_bounds__(512, 2) void deerskin(
    const float* __restrict__ Xr, const float* __restrict__ Xi,
    const float* __restrict__ Tg,
    const float* __restrict__ W0r, const float* __restrict__ W0i,
    const float* __restrict__ Phi0, const float* __restrict__ Beta0,
    float* __restrict__ outs, float* __restrict__ betas, float* __restrict__ gammas)
{
    // Only remaining LDS: 16-float double-buffered partial array.
    __shared__ __align__(16) float sP[16];

    const int n = threadIdx.x;
    const int lane = n & 63;
    const int wid = n >> 6;

    // W row in registers as v2f[16] per re/im so every hot op maps 1:1 onto
    // a v_pk_{mul,fma}_f32.
    v2f wr2[16], wi2[16];
    {
        const v2f* wr0 = (const v2f*)(W0r + n * DD);
        const v2f* wi0 = (const v2f*)(W0i + n * DD);
#pragma unroll
        for (int k = 0; k < 16; ++k) { wr2[k] = wr0[k]; wi2[k] = wi0[k]; }
    }
    float phi = Phi0[n];
    float beta = Beta0[n];
    float lt = 0.0f;
    float err = 0.0f;

    // Loop-carried SGPR-resident x(t): 64 SGPRs + tgt. Single-buffered:
    // last read of x(t) is pre-barrier (matvec + tw); the x(t+1) s_loads
    // are issued post-barrier, so the in-order wave front guarantees no
    // write-after-read hazard, and the tie-wait at the top of step t+1
    // covers the RAW.
    v16f sxr0, sxr1, sxi0, sxi1;
    float stgt;

    // ---- prologue: issue x(0) scalar loads (drained by the t=0 tie-wait).
    SL16(sxr0, Xr, 0x0); SL16(sxr1, Xr, 0x40);
    SL16(sxi0, Xi, 0x0); SL16(sxi1, Xi, 0x40);
    SL1(stgt, Tg);

    for (int t = 0; t < TT; ++t) {
        // ---- 1. x-independent precompute (beta-dependent arm) ----
        const float gamma = __expf(-0.5f * beta);
        const float dtl = gamma * F_DT;
        lt += dtl;
        const float theta = fmaf(F_OMEGA, lt, phi);
        float rev = theta * F_INV_TWO_PI;
        rev -= floorf(rev);
        const float s = __builtin_amdgcn_sinf(rev);
        const float c = __builtin_amdgcn_cosf(rev);
        const float a_sA = 1.0f - __expf(-2.0f * F_DT * (gamma + 1e-6f));
        const float a_sB = 1.0f - __expf(-F_DT / 0.03f);

        // ---- 2. tie-wait for x(t): s_loads issued ~a full step ago ----
        asm volatile("s_waitcnt lgkmcnt(0)"
            : "+s"(sxr0), "+s"(sxr1), "+s"(sxi0), "+s"(sxi1), "+s"(stgt)
            :: "memory");
        const float tgt = stgt;

        v2f xr_[16], xi_[16];
        MKP(xr_, sxr0, sxr1);
        MKP(xi_, sxi0, sxi1);

        // ---- 3. Z = W @ x: 8 packed accumulator chains, VGPR(W) x SGPR(x),
        // same per-lane accumulation order as before ----
        v2f arr0, arr1, aii0, aii1, ari0, ari1, air0, air1;
        PK_MUL_VS(arr0, wr2[0], xr_[0]); PK_MUL_VS(arr1, wr2[1], xr_[1]);
        PK_MUL_VS(aii0, wi2[0], xi_[0]); PK_MUL_VS(aii1, wi2[1], xi_[1]);
        PK_MUL_VS(ari0, wr2[0], xi_[0]); PK_MUL_VS(ari1, wr2[1], xi_[1]);
        PK_MUL_VS(air0, wi2[0], xr_[0]); PK_MUL_VS(air1, wi2[1], xr_[1]);
#pragma unroll
        for (int k = 2; k < 16; k += 2) {
            PK_FMA_ACC_VS(arr0, wr2[k], xr_[k]); PK_FMA_ACC_VS(arr1, wr2[k + 1], xr_[k + 1]);
            PK_FMA_ACC_VS(aii0, wi2[k], xi_[k]); PK_FMA_ACC_VS(aii1, wi2[k + 1], xi_[k + 1]);
            PK_FMA_ACC_VS(ari0, wr2[k], xi_[k]); PK_FMA_ACC_VS(ari1, wr2[k + 1], xi_[k + 1]);
            PK_FMA_ACC_VS(air0, wi2[k], xr_[k]); PK_FMA_ACC_VS(air1, wi2[k + 1], xr_[k + 1]);
        }
        const float hArr = (arr0.x + arr0.y) + (arr1.x + arr1.y);
        const float hAii = (aii0.x + aii0.y) + (aii1.x + aii1.y);
        const float hAri = (ari0.x + ari0.y) + (ari1.x + ari1.y);
        const float hAir = (air0.x + air0.y) + (air1.x + air1.y);
        const float zr = hArr - hAii;
        const float zi = hAri + hAir;

        // Y = |Z| * relu(cos(theta - angle(Z))) == relu(zr*cos + zi*sin)
        const float Y = fmaxf(fmaf(zr, c, zi * s), 0.0f);

        // ---- 4. reduce 512 -> 1: DPP wave sum, 8 partials via LDS ----
        float v = wave_reduce_to_lane63(Y * c);
        if (lane == 63) sP[((t & 1) << 3) + wid] = v;

        // ---- 5. pre-barrier tail: tw = g*x (x-dependent W half), phi,
        // gamma store — all off the post-barrier critical path ----
        const float inv_t = 1.0f / (fabsf(tgt) + 0.01f);
        const float yy = Y * Y;
        const float g = 0.05f * Y * dtl;
        const v2f g2 = {g, g};
        v2f twr[16], twi[16];
#pragma unroll
        for (int q = 0; q < 16; ++q) {
            PK_MUL_VS(twr[q], g2, xr_[q]);
            PK_MUL_VS(twi[q], g2, xi_[q]);
        }
        phi += (2.0f / (float)NN) * (-tgt * s) * dtl;
        phi = phi - F_TWO_PI * floorf(phi * F_INV_TWO_PI);
        gammas[t * NN + n] = gamma;   // gamma from OLD beta, per reference

        // ---- 6. barrier (drains only lane63's sP ds_write) ----
        barrier_lgkm();

        // ---- 7. sP partial read (the only per-step LDS reads left) ----
        const unsigned lsp =
            (unsigned)(unsigned long long)(lds_f*)&sP[(t & 1) << 3];
        v4f p0, p1;
        DSR128(p0, lsp, 0); DSR128(p1, lsp, 16);
        asm volatile("s_waitcnt lgkmcnt(0)" : "+v"(p0), "+v"(p1) :: "memory");

        // ---- 8. prefetch x(t+1) into the same SGPRs (issued after the sP
        // wait so the counted-wait stays clean; drained by next tie-wait) ----
        {
            const int tn = (t + 1 < TT) ? (t + 1) : (TT - 1);
            const float* xrp = Xr + (size_t)tn * DD;
            const float* xip = Xi + (size_t)tn * DD;
            const float* tgp = Tg + tn;
            SL16(sxr0, xrp, 0x0); SL16(sxr1, xrp, 0x40);
            SL16(sxi0, xip, 0x0); SL16(sxi1, xip, 0x40);
            SL1(stgt, tgp);
        }

        // ---- 9. out + short scalar feedback chain ----
        const float out = ((p0.x + p0.y) + (p0.z + p0.w)) +
                          ((p1.x + p1.y) + (p1.z + p1.w));
        const float raw = fabsf(tgt - out);
        err = 0.99f * err + 0.01f * raw;
        const float rel = err * inv_t;
        const float btg = 3.5f * __expf(-5.0f * rel);
        const float a_s = (btg > beta) ? a_sA : a_sB;
        float bnew = beta + a_s * (btg - beta);
        bnew = fminf(fmaxf(bnew, 0.005f), 5.0f);

        // ---- 10. W = W*m1 + tw (same FP order as R0-R3) ----
        const float k = (bnew * yy) * dtl;
        const float m1 = 1.0f - k;
        const v2f m12 = {m1, m1};
#pragma unroll
        for (int q = 0; q < 16; ++q) {
            PK_FMA_W(wr2[q], m12, twr[q]);
            PK_FMA_W(wi2[q], m12, twi[q]);
        }

        // ---- 11. outputs (fire-and-forget; no vmcnt waits anywhere) ----
        betas[t * NN + n] = bnew;
        if (lane == 63) outs[t] = out;
        beta = bnew;
    }
}

extern "C" void kernel_launch(void* const* d_in, const int* in_sizes, int n_in,
                              void* d_out, int out_size, void* d_ws, size_t ws_size,
                              hipStream_t stream) {
    const float* Xr    = (const float*)d_in[0];   // [T, D]
    const float* Xi    = (const float*)d_in[1];   // [T, D]
    const float* Tg    = (const float*)d_in[2];   // [T]
    const float* W0r   = (const float*)d_in[3];   // [N, D]
    const float* W0i   = (const float*)d_in[4];   // [N, D]
    const float* Phi0  = (const float*)d_in[5];   // [N]
    const float* Beta0 = (const float*)d_in[6];   // [N]

    float* outs   = (float*)d_out;                // [T]
    float* betas  = outs + TT;                    // [T, N]
    float* gammas = betas + (size_t)TT * NN;      // [T, N]

    deerskin<<<1, NN, 0, stream>>>(Xr, Xi, Tg, W0r, W0i, Phi0, Beta0,
                                   outs, betas, gammas);
}